// Round 1
// baseline (5964.450 us; speedup 1.0000x reference)
//
#include <hip/hip_runtime.h>

#define D 128
#define HD 256
#define BN_EPS 1e-5f

__device__ __forceinline__ float4 ldg4(const float* p) {
    return *reinterpret_cast<const float4*>(p);
}

// ---------------------------------------------------------------------------
// K0: AtomEncoder  h[i] = atom_emb1[x[i,0]] + atom_emb2[x[i,1]]
// ---------------------------------------------------------------------------
__global__ __launch_bounds__(256) void k_atom(
    const int* __restrict__ x,
    const float* __restrict__ ae1, const float* __restrict__ ae2,
    float* __restrict__ h, int N)
{
    int idx = blockIdx.x * 256 + threadIdx.x;     // over N*32 float4 slots
    int row = idx >> 5;
    int d   = (idx & 31) * 4;
    if (row >= N) return;
    int i0 = x[row * 2 + 0];
    int i1 = x[row * 2 + 1];
    float4 a = ldg4(ae1 + (size_t)i0 * D + d);
    float4 b = ldg4(ae2 + (size_t)i1 * D + d);
    float4 o = {a.x + b.x, a.y + b.y, a.z + b.z, a.w + b.w};
    *reinterpret_cast<float4*>(h + (size_t)row * D + d) = o;
}

// ---------------------------------------------------------------------------
// K1: agg[i] = h[i] + (bond_emb1[l][6] + bond_emb2[l][3])   (self-loop folded)
//     block 0 zeros this layer's stats slice (2*D floats)
// ---------------------------------------------------------------------------
__global__ __launch_bounds__(256) void k_init(
    const float* __restrict__ h,
    const float* __restrict__ c1, const float* __restrict__ c2, // rows 6 / 3
    float* __restrict__ agg, float* __restrict__ stats, int N)
{
    if (blockIdx.x == 0 && threadIdx.x < 2 * D) stats[threadIdx.x] = 0.f;
    int idx = blockIdx.x * 256 + threadIdx.x;
    int row = idx >> 5;
    int d   = (idx & 31) * 4;
    if (row >= N) return;
    float4 hv = ldg4(h  + (size_t)row * D + d);
    float4 a  = ldg4(c1 + d);
    float4 b  = ldg4(c2 + d);
    float4 o = {hv.x + a.x + b.x, hv.y + a.y + b.y,
                hv.z + a.z + b.z, hv.w + a.w + b.w};
    *reinterpret_cast<float4*>(agg + (size_t)row * D + d) = o;
}

// ---------------------------------------------------------------------------
// K2: edge scatter: agg[dst] += h[src] + be1[ea0] + be2[ea1]   (atomics)
//     32 threads per edge, float4 per thread
// ---------------------------------------------------------------------------
__global__ __launch_bounds__(256) void k_scatter(
    const int* __restrict__ ei, const int* __restrict__ ea,
    const float* __restrict__ h,
    const float* __restrict__ be1, const float* __restrict__ be2,
    float* __restrict__ agg, int E)
{
    int idx = blockIdx.x * 256 + threadIdx.x;     // over E*32
    int e = idx >> 5;
    int d = (idx & 31) * 4;
    if (e >= E) return;
    int src = ei[e];
    int dst = ei[E + e];
    int a0  = ea[e * 2 + 0];
    int a1  = ea[e * 2 + 1];
    float4 hv = ldg4(h   + (size_t)src * D + d);
    float4 e1 = ldg4(be1 + (size_t)a0  * D + d);
    float4 e2 = ldg4(be2 + (size_t)a1  * D + d);
    float* out = agg + (size_t)dst * D + d;
    atomicAdd(out + 0, hv.x + e1.x + e2.x);
    atomicAdd(out + 1, hv.y + e1.y + e2.y);
    atomicAdd(out + 2, hv.z + e1.z + e2.z);
    atomicAdd(out + 3, hv.w + e1.w + e2.w);
}

// ---------------------------------------------------------------------------
// K3: fused MLP: h2 = relu(agg@W1 + b1)@W2 + b2, + column sum/sumsq for BN.
//     32 rows per block, 256 threads. Hidden tile lives in LDS only.
//     agg_in and h2_out may alias (block reads its rows fully before writing).
// ---------------------------------------------------------------------------
__global__ __launch_bounds__(256) void k_mlp(
    const float* agg_in, float* h2_out,
    const float* __restrict__ W1, const float* __restrict__ b1,
    const float* __restrict__ W2, const float* __restrict__ b2,
    float* __restrict__ stats, int N)
{
    __shared__ float a_lds[32][D + 4];
    __shared__ float hid_lds[32][HD + 4];
    __shared__ float s_sum[D];
    __shared__ float s_sq[D];

    int t = threadIdx.x;
    int row0 = blockIdx.x * 32;
    if (t < D) { s_sum[t] = 0.f; s_sq[t] = 0.f; }

    // stage A tile (32 x 128)
    for (int i = t; i < 32 * 32; i += 256) {
        int r = i >> 5;
        int c = (i & 31) * 4;
        int row = row0 + r;
        float4 v = {0.f, 0.f, 0.f, 0.f};
        if (row < N) v = ldg4(agg_in + (size_t)row * D + c);
        *reinterpret_cast<float4*>(&a_lds[r][c]) = v;
    }
    __syncthreads();

    int tr4 = (t >> 5) * 4;   // base row (0,4,...,28)
    int tc  = t & 31;         // col group

    // ---- GEMM1: [32x128] x [128x256] ----
    float acc1[4][8];
#pragma unroll
    for (int r = 0; r < 4; ++r)
#pragma unroll
        for (int c = 0; c < 8; ++c) acc1[r][c] = 0.f;

#pragma unroll 4
    for (int k = 0; k < D; ++k) {
        float a0 = a_lds[tr4 + 0][k];
        float a1 = a_lds[tr4 + 1][k];
        float a2 = a_lds[tr4 + 2][k];
        float a3 = a_lds[tr4 + 3][k];
        float w[8];
        *reinterpret_cast<float4*>(&w[0]) = ldg4(W1 + (size_t)k * HD + tc * 8);
        *reinterpret_cast<float4*>(&w[4]) = ldg4(W1 + (size_t)k * HD + tc * 8 + 4);
#pragma unroll
        for (int c = 0; c < 8; ++c) {
            acc1[0][c] = fmaf(a0, w[c], acc1[0][c]);
            acc1[1][c] = fmaf(a1, w[c], acc1[1][c]);
            acc1[2][c] = fmaf(a2, w[c], acc1[2][c]);
            acc1[3][c] = fmaf(a3, w[c], acc1[3][c]);
        }
    }

    float bias1[8];
    *reinterpret_cast<float4*>(&bias1[0]) = ldg4(b1 + tc * 8);
    *reinterpret_cast<float4*>(&bias1[4]) = ldg4(b1 + tc * 8 + 4);
#pragma unroll
    for (int r = 0; r < 4; ++r)
#pragma unroll
        for (int c = 0; c < 8; ++c) {
            float v = acc1[r][c] + bias1[c];
            hid_lds[tr4 + r][tc * 8 + c] = v > 0.f ? v : 0.f;
        }
    __syncthreads();

    // ---- GEMM2: [32x256] x [256x128] ----
    float acc2[4][4];
#pragma unroll
    for (int r = 0; r < 4; ++r)
#pragma unroll
        for (int c = 0; c < 4; ++c) acc2[r][c] = 0.f;

#pragma unroll 4
    for (int k = 0; k < HD; ++k) {
        float a0 = hid_lds[tr4 + 0][k];
        float a1 = hid_lds[tr4 + 1][k];
        float a2 = hid_lds[tr4 + 2][k];
        float a3 = hid_lds[tr4 + 3][k];
        float w[4];
        *reinterpret_cast<float4*>(&w[0]) = ldg4(W2 + (size_t)k * D + tc * 4);
#pragma unroll
        for (int c = 0; c < 4; ++c) {
            acc2[0][c] = fmaf(a0, w[c], acc2[0][c]);
            acc2[1][c] = fmaf(a1, w[c], acc2[1][c]);
            acc2[2][c] = fmaf(a2, w[c], acc2[2][c]);
            acc2[3][c] = fmaf(a3, w[c], acc2[3][c]);
        }
    }

    float bias2[4];
    *reinterpret_cast<float4*>(&bias2[0]) = ldg4(b2 + tc * 4);

    float csum[4] = {0.f, 0.f, 0.f, 0.f};
    float csq[4]  = {0.f, 0.f, 0.f, 0.f};
#pragma unroll
    for (int r = 0; r < 4; ++r) {
        int row = row0 + tr4 + r;
        if (row < N) {
            float v0 = acc2[r][0] + bias2[0];
            float v1 = acc2[r][1] + bias2[1];
            float v2 = acc2[r][2] + bias2[2];
            float v3 = acc2[r][3] + bias2[3];
            csum[0] += v0; csq[0] += v0 * v0;
            csum[1] += v1; csq[1] += v1 * v1;
            csum[2] += v2; csq[2] += v2 * v2;
            csum[3] += v3; csq[3] += v3 * v3;
            float4 o = {v0, v1, v2, v3};
            *reinterpret_cast<float4*>(h2_out + (size_t)row * D + tc * 4) = o;
        }
    }
#pragma unroll
    for (int c = 0; c < 4; ++c) {
        atomicAdd(&s_sum[tc * 4 + c], csum[c]);
        atomicAdd(&s_sq[tc * 4 + c],  csq[c]);
    }
    __syncthreads();
    if (t < D) {
        atomicAdd(stats + t,     s_sum[t]);
        atomicAdd(stats + D + t, s_sq[t]);
    }
}

// ---------------------------------------------------------------------------
// K4a: BN prep — scale[d], shift[d] from sums (1 block, 128 threads)
// ---------------------------------------------------------------------------
__global__ __launch_bounds__(128) void k_bnprep(
    const float* __restrict__ stats,       // [2*D] sums
    const float* __restrict__ gamma, const float* __restrict__ beta,
    float* __restrict__ ss,                // out: [2*D] scale, shift
    float inv_n)
{
    int d = threadIdx.x;
    float mu  = stats[d] * inv_n;
    float var = stats[D + d] * inv_n - mu * mu;
    float sc  = rsqrtf(var + BN_EPS) * gamma[d];
    ss[d]     = sc;
    ss[D + d] = beta[d] - mu * sc;
}

// ---------------------------------------------------------------------------
// K4b: normalize: h = h2*scale + shift  (+ relu except last layer)
// ---------------------------------------------------------------------------
__global__ __launch_bounds__(256) void k_bn(
    const float* __restrict__ h2, const float* __restrict__ ss,
    float* __restrict__ h, int N, int do_relu)
{
    int idx = blockIdx.x * 256 + threadIdx.x;
    int row = idx >> 5;
    int d   = (idx & 31) * 4;
    if (row >= N) return;
    float4 v  = ldg4(h2 + (size_t)row * D + d);
    float4 sc = ldg4(ss + d);
    float4 sh = ldg4(ss + D + d);
    float4 o;
    o.x = fmaf(v.x, sc.x, sh.x);
    o.y = fmaf(v.y, sc.y, sh.y);
    o.z = fmaf(v.z, sc.z, sh.z);
    o.w = fmaf(v.w, sc.w, sh.w);
    if (do_relu) {
        o.x = o.x > 0.f ? o.x : 0.f;
        o.y = o.y > 0.f ? o.y : 0.f;
        o.z = o.z > 0.f ? o.z : 0.f;
        o.w = o.w > 0.f ? o.w : 0.f;
    }
    *reinterpret_cast<float4*>(h + (size_t)row * D + d) = o;
}

// ---------------------------------------------------------------------------
extern "C" void kernel_launch(void* const* d_in, const int* in_sizes, int n_in,
                              void* d_out, int out_size, void* d_ws, size_t ws_size,
                              hipStream_t stream)
{
    const int*   x     = (const int*)  d_in[0];
    const int*   ei    = (const int*)  d_in[1];
    const int*   ea    = (const int*)  d_in[2];
    const float* ae1   = (const float*)d_in[3];
    const float* ae2   = (const float*)d_in[4];
    const float* be1   = (const float*)d_in[5];   // [5,7,128]
    const float* be2   = (const float*)d_in[6];   // [5,4,128]
    const float* W1    = (const float*)d_in[7];   // [5,128,256]
    const float* b1    = (const float*)d_in[8];   // [5,256]
    const float* W2    = (const float*)d_in[9];   // [5,256,128]
    const float* b2    = (const float*)d_in[10];  // [5,128]
    const float* gamma = (const float*)d_in[11];  // [5,128]
    const float* beta  = (const float*)d_in[12];  // [5,128]

    const int N = in_sizes[0] / 2;
    const int E = in_sizes[1] / 2;

    float* h   = (float*)d_out;                 // persistent node features
    float* agg = (float*)d_ws;                  // [N, D]
    // layout after agg: stats (5 * 2D) then scale/shift (2D) then optional h2
    float* stats_base = agg + (size_t)N * D;
    float* ss         = stats_base + 5 * 2 * D;
    size_t base_floats = (size_t)N * D + 5 * 2 * D + 2 * D;
    // use a separate h2 buffer if workspace is big enough, else alias with agg
    float* h2 = agg;
    if (ws_size >= (base_floats + (size_t)N * D) * sizeof(float))
        h2 = (float*)d_ws + base_floats;

    const dim3 blk(256);
    const int nb_nodes = (N * 32 + 255) / 256;
    const int nb_edges = (E * 32 + 255) / 256;
    const int nb_mlp   = (N + 31) / 32;
    const float inv_n  = 1.0f / (float)N;

    k_atom<<<nb_nodes, blk, 0, stream>>>(x, ae1, ae2, h, N);

    for (int l = 0; l < 5; ++l) {
        const float* be1l = be1 + (size_t)l * 7 * D;
        const float* be2l = be2 + (size_t)l * 4 * D;
        float* st = stats_base + (size_t)l * 2 * D;

        k_init<<<nb_nodes, blk, 0, stream>>>(h, be1l + 6 * D, be2l + 3 * D,
                                             agg, st, N);
        k_scatter<<<nb_edges, blk, 0, stream>>>(ei, ea, h, be1l, be2l, agg, E);
        k_mlp<<<nb_mlp, blk, 0, stream>>>(agg, h2,
                                          W1 + (size_t)l * D * HD, b1 + (size_t)l * HD,
                                          W2 + (size_t)l * HD * D, b2 + (size_t)l * D,
                                          st, N);
        k_bnprep<<<1, 128, 0, stream>>>(st, gamma + (size_t)l * D,
                                        beta + (size_t)l * D, ss, inv_n);
        k_bn<<<nb_nodes, blk, 0, stream>>>(h2, ss, h, N, (l < 4) ? 1 : 0);
    }
}

// Round 3
// 1287.485 us; speedup vs baseline: 4.6326x; 4.6326x over previous
//
#include <hip/hip_runtime.h>

#define D 128
#define HD 256
#define BN_EPS 1e-5f

__device__ __forceinline__ float4 ldg4(const float* p) {
    return *reinterpret_cast<const float4*>(p);
}

// ---------------------------------------------------------------------------
// K0: AtomEncoder  h[i] = atom_emb1[x[i,0]] + atom_emb2[x[i,1]]
// ---------------------------------------------------------------------------
__global__ __launch_bounds__(256) void k_atom(
    const int* __restrict__ x,
    const float* __restrict__ ae1, const float* __restrict__ ae2,
    float* __restrict__ h, int N)
{
    int idx = blockIdx.x * 256 + threadIdx.x;     // over N*32 float4 slots
    int row = idx >> 5;
    int d   = (idx & 31) * 4;
    if (row >= N) return;
    int i0 = x[row * 2 + 0];
    int i1 = x[row * 2 + 1];
    float4 a = ldg4(ae1 + (size_t)i0 * D + d);
    float4 b = ldg4(ae2 + (size_t)i1 * D + d);
    float4 o = {a.x + b.x, a.y + b.y, a.z + b.z, a.w + b.w};
    *reinterpret_cast<float4*>(h + (size_t)row * D + d) = o;
}

// ---------------------------------------------------------------------------
// CSR build 1: per-edge histogram into rowptr[dst+1] + per-(dst,combo) counts
// ---------------------------------------------------------------------------
__global__ __launch_bounds__(256) void k_hist(
    const int* __restrict__ ei, const int* __restrict__ ea,
    int* __restrict__ rowptr, int* __restrict__ counts, int E)
{
    int e = blockIdx.x * 256 + threadIdx.x;
    if (e >= E) return;
    int dst = ei[E + e];
    atomicAdd(&rowptr[dst + 1], 1);
    int c = ea[2 * e] * 3 + ea[2 * e + 1];      // edge_attr values are 0..2
    atomicAdd(&counts[dst * 9 + c], 1);
}

// ---------------------------------------------------------------------------
// CSR build 2: single-block prefix sum. rowptr[i+1] holds deg[i] on entry;
// on exit rowptr is the inclusive prefix (rowptr[0]=0) and cursor[i] the
// exclusive prefix (fill cursor). Wave-level shfl scan.
// ---------------------------------------------------------------------------
__global__ __launch_bounds__(1024) void k_scan(
    int* __restrict__ rowptr, int* __restrict__ cursor, int N)
{
    __shared__ int wsum[16];
    __shared__ int wincl[16];
    __shared__ int s_carry;
    int t = threadIdx.x;
    int lane = t & 63, w = t >> 6;
    if (t == 0) s_carry = 0;
    __syncthreads();

    for (int base = 0; base < N; base += 1024) {
        int i = base + t;
        int v = (i < N) ? rowptr[i + 1] : 0;
        int incl = v;
#pragma unroll
        for (int off = 1; off < 64; off <<= 1) {
            int y = __shfl_up(incl, off);
            if (lane >= off) incl += y;
        }
        if (lane == 63) wsum[w] = incl;
        __syncthreads();                       // A
        if (t < 16) {
            int x = wsum[t];
#pragma unroll
            for (int off = 1; off < 16; off <<= 1) {
                int y = __shfl_up(x, off);
                if (t >= off) x += y;
            }
            wincl[t] = x;
        }
        __syncthreads();                       // B
        int woff  = (w == 0) ? 0 : wincl[w - 1];
        int carry = s_carry;
        int full  = carry + woff + incl;
        if (i < N) {
            rowptr[i + 1] = full;
            cursor[i]     = full - v;
        }
        __syncthreads();                       // C
        if (t == 0) s_carry = carry + wincl[15];
        __syncthreads();
    }
    if (t == 0) rowptr[0] = 0;
}

// ---------------------------------------------------------------------------
// CSR build 3: scatter edge sources into CSR order via atomic cursors
// ---------------------------------------------------------------------------
__global__ __launch_bounds__(256) void k_fill(
    const int* __restrict__ ei, int* __restrict__ cursor,
    int* __restrict__ esrc, int E)
{
    int e = blockIdx.x * 256 + threadIdx.x;
    if (e >= E) return;
    int dst = ei[E + e];
    int pos = atomicAdd(&cursor[dst], 1);
    esrc[pos] = ei[e];
}

// ---------------------------------------------------------------------------
// bec precompute: bec[l][c][d], c=0..8 -> be1[c/3]+be2[c%3], c=9 -> self-loop
// ---------------------------------------------------------------------------
__global__ __launch_bounds__(256) void k_bec(
    const float* __restrict__ be1, const float* __restrict__ be2,
    float* __restrict__ bec)
{
    int idx = blockIdx.x * 256 + threadIdx.x;   // 5*10*128 = 6400
    if (idx >= 5 * 10 * D) return;
    int d  = idx & (D - 1);
    int lc = idx >> 7;
    int l = lc / 10, c = lc % 10;
    int a0 = (c == 9) ? 6 : (c / 3);
    int a1 = (c == 9) ? 3 : (c % 3);
    bec[idx] = be1[((size_t)l * 7 + a0) * D + d] + be2[((size_t)l * 4 + a1) * D + d];
}

// ---------------------------------------------------------------------------
// K2': fused init + gather aggregation (no atomics):
//  agg[i] = h[i] + bec[9] + sum_c counts[i][c]*bec[c] + sum_{e in CSR[i]} h[src]
//  32 lanes per node (float4/lane), 8 nodes per block. CSR loop unrolled x4
//  to keep 4 independent loads in flight per lane (L2/L3 latency hiding).
// ---------------------------------------------------------------------------
__global__ __launch_bounds__(256) void k_gather(
    const float* __restrict__ h, const int* __restrict__ rowptr,
    const int* __restrict__ esrc, const int* __restrict__ counts,
    const float* __restrict__ bec,          // [10][D], this layer
    float* __restrict__ agg, int N)
{
    int g = threadIdx.x >> 5;
    int lane = threadIdx.x & 31;
    int d = lane * 4;
    int node = blockIdx.x * 8 + g;
    if (node >= N) return;

    float4 acc = ldg4(h + (size_t)node * D + d);
    float4 sl  = ldg4(bec + 9 * D + d);
    acc.x += sl.x; acc.y += sl.y; acc.z += sl.z; acc.w += sl.w;

#pragma unroll
    for (int c = 0; c < 9; ++c) {
        float fc = (float)counts[node * 9 + c];
        float4 b = ldg4(bec + c * D + d);
        acc.x = fmaf(fc, b.x, acc.x);
        acc.y = fmaf(fc, b.y, acc.y);
        acc.z = fmaf(fc, b.z, acc.z);
        acc.w = fmaf(fc, b.w, acc.w);
    }

    int beg = rowptr[node], end = rowptr[node + 1];
    int e = beg;
    for (; e + 3 < end; e += 4) {
        int s0 = esrc[e], s1 = esrc[e + 1], s2 = esrc[e + 2], s3 = esrc[e + 3];
        float4 h0 = ldg4(h + (size_t)s0 * D + d);
        float4 h1 = ldg4(h + (size_t)s1 * D + d);
        float4 h2 = ldg4(h + (size_t)s2 * D + d);
        float4 h3 = ldg4(h + (size_t)s3 * D + d);
        acc.x += (h0.x + h1.x) + (h2.x + h3.x);
        acc.y += (h0.y + h1.y) + (h2.y + h3.y);
        acc.z += (h0.z + h1.z) + (h2.z + h3.z);
        acc.w += (h0.w + h1.w) + (h2.w + h3.w);
    }
    for (; e < end; ++e) {
        float4 h0 = ldg4(h + (size_t)esrc[e] * D + d);
        acc.x += h0.x; acc.y += h0.y; acc.z += h0.z; acc.w += h0.w;
    }
    *reinterpret_cast<float4*>(agg + (size_t)node * D + d) = acc;
}

// ---------------------------------------------------------------------------
// K3: fused MLP: h2 = relu(agg@W1 + b1)@W2 + b2, + column sum/sumsq for BN.
//     32 rows per block, 256 threads. Hidden tile lives in LDS only.
//     agg_in and h2_out may alias (block reads its rows fully before writing).
// ---------------------------------------------------------------------------
__global__ __launch_bounds__(256) void k_mlp(
    const float* agg_in, float* h2_out,
    const float* __restrict__ W1, const float* __restrict__ b1,
    const float* __restrict__ W2, const float* __restrict__ b2,
    float* __restrict__ stats, int N)
{
    __shared__ float a_lds[32][D + 4];
    __shared__ float hid_lds[32][HD + 4];
    __shared__ float s_sum[D];
    __shared__ float s_sq[D];

    int t = threadIdx.x;
    int row0 = blockIdx.x * 32;
    if (t < D) { s_sum[t] = 0.f; s_sq[t] = 0.f; }

    for (int i = t; i < 32 * 32; i += 256) {
        int r = i >> 5;
        int c = (i & 31) * 4;
        int row = row0 + r;
        float4 v = {0.f, 0.f, 0.f, 0.f};
        if (row < N) v = ldg4(agg_in + (size_t)row * D + c);
        *reinterpret_cast<float4*>(&a_lds[r][c]) = v;
    }
    __syncthreads();

    int tr4 = (t >> 5) * 4;
    int tc  = t & 31;

    float acc1[4][8];
#pragma unroll
    for (int r = 0; r < 4; ++r)
#pragma unroll
        for (int c = 0; c < 8; ++c) acc1[r][c] = 0.f;

#pragma unroll 4
    for (int k = 0; k < D; ++k) {
        float a0 = a_lds[tr4 + 0][k];
        float a1 = a_lds[tr4 + 1][k];
        float a2 = a_lds[tr4 + 2][k];
        float a3 = a_lds[tr4 + 3][k];
        float w[8];
        *reinterpret_cast<float4*>(&w[0]) = ldg4(W1 + (size_t)k * HD + tc * 8);
        *reinterpret_cast<float4*>(&w[4]) = ldg4(W1 + (size_t)k * HD + tc * 8 + 4);
#pragma unroll
        for (int c = 0; c < 8; ++c) {
            acc1[0][c] = fmaf(a0, w[c], acc1[0][c]);
            acc1[1][c] = fmaf(a1, w[c], acc1[1][c]);
            acc1[2][c] = fmaf(a2, w[c], acc1[2][c]);
            acc1[3][c] = fmaf(a3, w[c], acc1[3][c]);
        }
    }

    float bias1[8];
    *reinterpret_cast<float4*>(&bias1[0]) = ldg4(b1 + tc * 8);
    *reinterpret_cast<float4*>(&bias1[4]) = ldg4(b1 + tc * 8 + 4);
#pragma unroll
    for (int r = 0; r < 4; ++r)
#pragma unroll
        for (int c = 0; c < 8; ++c) {
            float v = acc1[r][c] + bias1[c];
            hid_lds[tr4 + r][tc * 8 + c] = v > 0.f ? v : 0.f;
        }
    __syncthreads();

    float acc2[4][4];
#pragma unroll
    for (int r = 0; r < 4; ++r)
#pragma unroll
        for (int c = 0; c < 4; ++c) acc2[r][c] = 0.f;

#pragma unroll 4
    for (int k = 0; k < HD; ++k) {
        float a0 = hid_lds[tr4 + 0][k];
        float a1 = hid_lds[tr4 + 1][k];
        float a2 = hid_lds[tr4 + 2][k];
        float a3 = hid_lds[tr4 + 3][k];
        float w[4];
        *reinterpret_cast<float4*>(&w[0]) = ldg4(W2 + (size_t)k * D + tc * 4);
#pragma unroll
        for (int c = 0; c < 4; ++c) {
            acc2[0][c] = fmaf(a0, w[c], acc2[0][c]);
            acc2[1][c] = fmaf(a1, w[c], acc2[1][c]);
            acc2[2][c] = fmaf(a2, w[c], acc2[2][c]);
            acc2[3][c] = fmaf(a3, w[c], acc2[3][c]);
        }
    }

    float bias2[4];
    *reinterpret_cast<float4*>(&bias2[0]) = ldg4(b2 + tc * 4);

    float csum[4] = {0.f, 0.f, 0.f, 0.f};
    float csq[4]  = {0.f, 0.f, 0.f, 0.f};
#pragma unroll
    for (int r = 0; r < 4; ++r) {
        int row = row0 + tr4 + r;
        if (row < N) {
            float v0 = acc2[r][0] + bias2[0];
            float v1 = acc2[r][1] + bias2[1];
            float v2 = acc2[r][2] + bias2[2];
            float v3 = acc2[r][3] + bias2[3];
            csum[0] += v0; csq[0] += v0 * v0;
            csum[1] += v1; csq[1] += v1 * v1;
            csum[2] += v2; csq[2] += v2 * v2;
            csum[3] += v3; csq[3] += v3 * v3;
            float4 o = {v0, v1, v2, v3};
            *reinterpret_cast<float4*>(h2_out + (size_t)row * D + tc * 4) = o;
        }
    }
#pragma unroll
    for (int c = 0; c < 4; ++c) {
        atomicAdd(&s_sum[tc * 4 + c], csum[c]);
        atomicAdd(&s_sq[tc * 4 + c],  csq[c]);
    }
    __syncthreads();
    if (t < D) {
        atomicAdd(stats + t,     s_sum[t]);
        atomicAdd(stats + D + t, s_sq[t]);
    }
}

// ---------------------------------------------------------------------------
// K4a: BN prep — scale/shift from sums (1 block, 128 threads)
// ---------------------------------------------------------------------------
__global__ __launch_bounds__(128) void k_bnprep(
    const float* __restrict__ stats,
    const float* __restrict__ gamma, const float* __restrict__ beta,
    float* __restrict__ ss, float inv_n)
{
    int d = threadIdx.x;
    float mu  = stats[d] * inv_n;
    float var = stats[D + d] * inv_n - mu * mu;
    float sc  = rsqrtf(var + BN_EPS) * gamma[d];
    ss[d]     = sc;
    ss[D + d] = beta[d] - mu * sc;
}

// ---------------------------------------------------------------------------
// K4b: normalize: h = h2*scale + shift  (+ relu except last layer)
// ---------------------------------------------------------------------------
__global__ __launch_bounds__(256) void k_bn(
    const float* __restrict__ h2, const float* __restrict__ ss,
    float* __restrict__ h, int N, int do_relu)
{
    int idx = blockIdx.x * 256 + threadIdx.x;
    int row = idx >> 5;
    int d   = (idx & 31) * 4;
    if (row >= N) return;
    float4 v  = ldg4(h2 + (size_t)row * D + d);
    float4 sc = ldg4(ss + d);
    float4 sh = ldg4(ss + D + d);
    float4 o;
    o.x = fmaf(v.x, sc.x, sh.x);
    o.y = fmaf(v.y, sc.y, sh.y);
    o.z = fmaf(v.z, sc.z, sh.z);
    o.w = fmaf(v.w, sc.w, sh.w);
    if (do_relu) {
        o.x = o.x > 0.f ? o.x : 0.f;
        o.y = o.y > 0.f ? o.y : 0.f;
        o.z = o.z > 0.f ? o.z : 0.f;
        o.w = o.w > 0.f ? o.w : 0.f;
    }
    *reinterpret_cast<float4*>(h + (size_t)row * D + d) = o;
}

// ---------------------------------------------------------------------------
extern "C" void kernel_launch(void* const* d_in, const int* in_sizes, int n_in,
                              void* d_out, int out_size, void* d_ws, size_t ws_size,
                              hipStream_t stream)
{
    const int*   x     = (const int*)  d_in[0];
    const int*   ei    = (const int*)  d_in[1];
    const int*   ea    = (const int*)  d_in[2];
    const float* ae1   = (const float*)d_in[3];
    const float* ae2   = (const float*)d_in[4];
    const float* be1   = (const float*)d_in[5];   // [5,7,128]
    const float* be2   = (const float*)d_in[6];   // [5,4,128]
    const float* W1    = (const float*)d_in[7];   // [5,128,256]
    const float* b1    = (const float*)d_in[8];   // [5,256]
    const float* W2    = (const float*)d_in[9];   // [5,256,128]
    const float* b2    = (const float*)d_in[10];  // [5,128]
    const float* gamma = (const float*)d_in[11];  // [5,128]
    const float* beta  = (const float*)d_in[12];  // [5,128]

    const int N = in_sizes[0] / 2;
    const int E = in_sizes[1] / 2;

    float* h = (float*)d_out;

    // ---- workspace layout (4-byte elements, all regions 16B-aligned) ----
    const size_t n_rowptr = ((size_t)N + 1 + 3) & ~(size_t)3;
    const size_t n_counts = (size_t)N * 9;
    const size_t n_stats  = 5 * 2 * D;
    const size_t n_ss     = 2 * D;
    const size_t n_cursor = (size_t)N;
    const size_t n_esrc   = ((size_t)E + 3) & ~(size_t)3;
    const size_t n_bec    = 5 * 10 * D;

    char* wsb = (char*)d_ws;
    int*   rowptr = (int*)wsb;
    int*   counts = rowptr + n_rowptr;
    float* stats  = (float*)(counts + n_counts);
    float* ss     = stats + n_stats;
    int*   cursor = (int*)(ss + n_ss);
    int*   esrc   = cursor + n_cursor;
    float* bec    = (float*)(esrc + n_esrc);
    float* agg    = bec + n_bec;

    const size_t fixed_elems = n_rowptr + n_counts + n_stats + n_ss +
                               n_cursor + n_esrc + n_bec;
    float* h2 = agg;   // alias fallback (safe: k_mlp reads its rows first)
    if (ws_size >= (fixed_elems + 2 * (size_t)N * D) * 4)
        h2 = agg + (size_t)N * D;

    // zero: rowptr + counts + stats (one contiguous region)
    hipMemsetAsync(rowptr, 0, (n_rowptr + n_counts + n_stats) * 4, stream);

    const dim3 blk(256);
    const int nb_nodes  = (N * 32 + 255) / 256;
    const int nb_edges  = (E + 255) / 256;
    const int nb_gather = (N + 7) / 8;
    const int nb_mlp    = (N + 31) / 32;
    const float inv_n   = 1.0f / (float)N;

    k_atom<<<nb_nodes, blk, 0, stream>>>(x, ae1, ae2, h, N);
    k_hist<<<nb_edges, blk, 0, stream>>>(ei, ea, rowptr, counts, E);
    k_scan<<<1, 1024, 0, stream>>>(rowptr, cursor, N);
    k_fill<<<nb_edges, blk, 0, stream>>>(ei, cursor, esrc, E);
    k_bec<<<(5 * 10 * D + 255) / 256, blk, 0, stream>>>(be1, be2, bec);

    for (int l = 0; l < 5; ++l) {
        float* st = stats + (size_t)l * 2 * D;
        k_gather<<<nb_gather, blk, 0, stream>>>(h, rowptr, esrc, counts,
                                                bec + (size_t)l * 10 * D, agg, N);
        k_mlp<<<nb_mlp, blk, 0, stream>>>(agg, h2,
                                          W1 + (size_t)l * D * HD, b1 + (size_t)l * HD,
                                          W2 + (size_t)l * HD * D, b2 + (size_t)l * D,
                                          st, N);
        k_bnprep<<<1, 128, 0, stream>>>(st, gamma + (size_t)l * D,
                                        beta + (size_t)l * D, ss, inv_n);
        k_bn<<<nb_nodes, blk, 0, stream>>>(h2, ss, h, N, (l < 4) ? 1 : 0);
    }
}

// Round 5
// 845.045 us; speedup vs baseline: 7.0581x; 1.5236x over previous
//
#include <hip/hip_runtime.h>

#define D 128
#define HD 256
#define BN_EPS 1e-5f

typedef __attribute__((ext_vector_type(8))) short bh8;
typedef __attribute__((ext_vector_type(4))) float f32x4;

__device__ __forceinline__ float4 ldg4(const float* p) {
    return *reinterpret_cast<const float4*>(p);
}
// bf16 RNE via bit ops (no bfloat16 header needed)
__device__ __forceinline__ unsigned short f2bf(float f) {
    union { float f; unsigned int u; } v; v.f = f;
    unsigned int u = v.u;
    return (unsigned short)((u + 0x7fffu + ((u >> 16) & 1u)) >> 16);
}
__device__ __forceinline__ float bf2f(unsigned short h) {
    union { unsigned int u; float f; } v; v.u = ((unsigned int)h) << 16; return v.f;
}

// ---------------------------------------------------------------------------
// K0: AtomEncoder  h[i] = atom_emb1[x[i,0]] + atom_emb2[x[i,1]]  -> d_out
// ---------------------------------------------------------------------------
__global__ __launch_bounds__(256) void k_atom(
    const int* __restrict__ x,
    const float* __restrict__ ae1, const float* __restrict__ ae2,
    float* __restrict__ h, int N)
{
    int idx = blockIdx.x * 256 + threadIdx.x;
    int row = idx >> 5;
    int d   = (idx & 31) * 4;
    if (row >= N) return;
    int i0 = x[row * 2 + 0];
    int i1 = x[row * 2 + 1];
    float4 a = ldg4(ae1 + (size_t)i0 * D + d);
    float4 b = ldg4(ae2 + (size_t)i1 * D + d);
    float4 o = {a.x + b.x, a.y + b.y, a.z + b.z, a.w + b.w};
    *reinterpret_cast<float4*>(h + (size_t)row * D + d) = o;
}

// ---------------------------------------------------------------------------
// CSR build 1: histogram degrees + per-(dst,combo) counts
// ---------------------------------------------------------------------------
__global__ __launch_bounds__(256) void k_hist(
    const int* __restrict__ ei, const int* __restrict__ ea,
    int* __restrict__ rowptr, int* __restrict__ counts, int E)
{
    int e = blockIdx.x * 256 + threadIdx.x;
    if (e >= E) return;
    int dst = ei[E + e];
    atomicAdd(&rowptr[dst + 1], 1);
    int c = ea[2 * e] * 3 + ea[2 * e + 1];
    atomicAdd(&counts[dst * 9 + c], 1);
}

// ---------------------------------------------------------------------------
// CSR build 2a/2b/2c: multi-block prefix sum (scan1 -> scan2 -> scan3)
// ---------------------------------------------------------------------------
__global__ __launch_bounds__(1024) void k_scan1(
    int* __restrict__ rowptr, int* __restrict__ cursor,
    int* __restrict__ bsum, int N)
{
    __shared__ int wsum[16];
    int t = threadIdx.x, lane = t & 63, w = t >> 6;
    int i = blockIdx.x * 1024 + t;
    int v = (i < N) ? rowptr[i + 1] : 0;
    int incl = v;
#pragma unroll
    for (int off = 1; off < 64; off <<= 1) {
        int y = __shfl_up(incl, off);
        if (lane >= off) incl += y;
    }
    if (lane == 63) wsum[w] = incl;
    __syncthreads();
    if (t < 16) {
        int xv = wsum[t];
#pragma unroll
        for (int off = 1; off < 16; off <<= 1) {
            int y = __shfl_up(xv, off);
            if (t >= off) xv += y;
        }
        wsum[t] = xv;
    }
    __syncthreads();
    int woff = w ? wsum[w - 1] : 0;
    int full = woff + incl;
    if (i < N) { rowptr[i + 1] = full; cursor[i] = full - v; }
    if (t == 1023) bsum[blockIdx.x] = full;
}

__global__ __launch_bounds__(64) void k_scan2(
    const int* __restrict__ bsum, int* __restrict__ boff, int nchunks)
{
    int t = threadIdx.x;
    int carry = 0;
    for (int base = 0; base < nchunks; base += 64) {
        int idx = base + t;
        int v = (idx < nchunks) ? bsum[idx] : 0;
        int incl = v;
#pragma unroll
        for (int off = 1; off < 64; off <<= 1) {
            int y = __shfl_up(incl, off);
            if (t >= off) incl += y;
        }
        if (idx < nchunks) boff[idx] = carry + incl - v;
        carry += __shfl(incl, 63);
    }
}

__global__ __launch_bounds__(1024) void k_scan3(
    int* __restrict__ rowptr, int* __restrict__ cursor,
    const int* __restrict__ boff, int N)
{
    int t = threadIdx.x;
    int i = blockIdx.x * 1024 + t;
    int off = boff[blockIdx.x];
    if (i < N) { rowptr[i + 1] += off; cursor[i] += off; }
    if (blockIdx.x == 0 && t == 0) rowptr[0] = 0;
}

// ---------------------------------------------------------------------------
// CSR build 3: fill edge sources in CSR order
// ---------------------------------------------------------------------------
__global__ __launch_bounds__(256) void k_fill(
    const int* __restrict__ ei, int* __restrict__ cursor,
    int* __restrict__ esrc, int E)
{
    int e = blockIdx.x * 256 + threadIdx.x;
    if (e >= E) return;
    int dst = ei[E + e];
    int pos = atomicAdd(&cursor[dst], 1);
    esrc[pos] = ei[e];
}

// ---------------------------------------------------------------------------
// bec precompute: bec[l][c][d], c=0..8 -> be1[c/3]+be2[c%3], c=9 -> self-loop
// ---------------------------------------------------------------------------
__global__ __launch_bounds__(256) void k_bec(
    const float* __restrict__ be1, const float* __restrict__ be2,
    float* __restrict__ bec)
{
    int idx = blockIdx.x * 256 + threadIdx.x;
    if (idx >= 5 * 10 * D) return;
    int d  = idx & (D - 1);
    int lc = idx >> 7;
    int l = lc / 10, c = lc % 10;
    int a0 = (c == 9) ? 6 : (c / 3);
    int a1 = (c == 9) ? 3 : (c % 3);
    bec[idx] = be1[((size_t)l * 7 + a0) * D + d] + be2[((size_t)l * 4 + a1) * D + d];
}

// ---------------------------------------------------------------------------
// Weight pack: split fp32 W into bf16 hi/lo, fragment-ordered for MFMA B.
// W1p frag (l,nt,kk,lane): 16 ushorts = [8 hi][8 lo], element j:
//   k = kk*32 + (lane>>4)*8 + j ; n = nt*16 + (lane&15)
// ---------------------------------------------------------------------------
__global__ __launch_bounds__(256) void k_wconv(
    const float* __restrict__ W1, const float* __restrict__ W2,
    unsigned short* __restrict__ W1p, unsigned short* __restrict__ W2p)
{
    int tid = blockIdx.x * 256 + threadIdx.x;
    if (tid >= 2 * 5 * 4096) return;
    bool isW2 = tid >= 5 * 4096;
    int r  = tid & 4095;
    int l  = (tid % (5 * 4096)) >> 12;
    int lane = r & 63;
    int l15 = lane & 15, l4 = lane >> 4;
    if (!isW2) {
        int nt = r >> 8;
        int kk = (r >> 6) & 3;
        int n = nt * 16 + l15;
        int kbase = kk * 32 + l4 * 8;
        unsigned short* out = W1p + (size_t)tid * 16;
        const float* src = W1 + ((size_t)l * D + kbase) * HD + n;
#pragma unroll
        for (int j = 0; j < 8; ++j) {
            float wv = src[(size_t)j * HD];
            unsigned short hi = f2bf(wv);
            unsigned short lo = f2bf(wv - bf2f(hi));
            out[j] = hi; out[8 + j] = lo;
        }
    } else {
        int nt = r >> 9;
        int kk = (r >> 6) & 7;
        int n = nt * 16 + l15;
        int kbase = kk * 32 + l4 * 8;
        unsigned short* out = W2p + (size_t)(l * 4096 + r) * 16;
        const float* src = W2 + ((size_t)l * HD + kbase) * D + n;
#pragma unroll
        for (int j = 0; j < 8; ++j) {
            float wv = src[(size_t)j * D];
            unsigned short hi = f2bf(wv);
            unsigned short lo = f2bf(wv - bf2f(hi));
            out[j] = hi; out[8 + j] = lo;
        }
    }
}

// ---------------------------------------------------------------------------
// Gather (+ fused BN affine + relu of previous layer), emits bf16 hi/lo agg.
// aggp row layout: 256 ushorts = [128 hi][128 lo].
// ---------------------------------------------------------------------------
template <int AFFINE>
__global__ __launch_bounds__(256) void k_gather(
    const float* __restrict__ hsrc, const int* __restrict__ rowptr,
    const int* __restrict__ esrc, const int* __restrict__ counts,
    const float* __restrict__ bec,          // [10][D] this layer
    const float* __restrict__ ss,           // [256] scale|shift (prev layer)
    unsigned short* __restrict__ aggp, int N)
{
    int g = threadIdx.x >> 5;
    int lane = threadIdx.x & 31;
    int d = lane * 4;
    int node = blockIdx.x * 8 + g;
    if (node >= N) return;

    float4 sc, sh;
    if (AFFINE) { sc = ldg4(ss + d); sh = ldg4(ss + D + d); }

    float4 acc = ldg4(hsrc + (size_t)node * D + d);
    if (AFFINE) {
        acc.x = fmaf(acc.x, sc.x, sh.x); acc.y = fmaf(acc.y, sc.y, sh.y);
        acc.z = fmaf(acc.z, sc.z, sh.z); acc.w = fmaf(acc.w, sc.w, sh.w);
        acc.x = acc.x > 0.f ? acc.x : 0.f; acc.y = acc.y > 0.f ? acc.y : 0.f;
        acc.z = acc.z > 0.f ? acc.z : 0.f; acc.w = acc.w > 0.f ? acc.w : 0.f;
    }
    float4 sl = ldg4(bec + 9 * D + d);
    acc.x += sl.x; acc.y += sl.y; acc.z += sl.z; acc.w += sl.w;

#pragma unroll
    for (int c = 0; c < 9; ++c) {
        float fc = (float)counts[node * 9 + c];
        float4 b = ldg4(bec + c * D + d);
        acc.x = fmaf(fc, b.x, acc.x);
        acc.y = fmaf(fc, b.y, acc.y);
        acc.z = fmaf(fc, b.z, acc.z);
        acc.w = fmaf(fc, b.w, acc.w);
    }

    int beg = rowptr[node], end = rowptr[node + 1];
    int e = beg;
    for (; e + 3 < end; e += 4) {
        int s0 = esrc[e], s1 = esrc[e + 1], s2 = esrc[e + 2], s3 = esrc[e + 3];
        float4 h0 = ldg4(hsrc + (size_t)s0 * D + d);
        float4 h1 = ldg4(hsrc + (size_t)s1 * D + d);
        float4 h2 = ldg4(hsrc + (size_t)s2 * D + d);
        float4 h3 = ldg4(hsrc + (size_t)s3 * D + d);
        if (AFFINE) {
            h0.x = fmaf(h0.x, sc.x, sh.x); h0.y = fmaf(h0.y, sc.y, sh.y);
            h0.z = fmaf(h0.z, sc.z, sh.z); h0.w = fmaf(h0.w, sc.w, sh.w);
            h1.x = fmaf(h1.x, sc.x, sh.x); h1.y = fmaf(h1.y, sc.y, sh.y);
            h1.z = fmaf(h1.z, sc.z, sh.z); h1.w = fmaf(h1.w, sc.w, sh.w);
            h2.x = fmaf(h2.x, sc.x, sh.x); h2.y = fmaf(h2.y, sc.y, sh.y);
            h2.z = fmaf(h2.z, sc.z, sh.z); h2.w = fmaf(h2.w, sc.w, sh.w);
            h3.x = fmaf(h3.x, sc.x, sh.x); h3.y = fmaf(h3.y, sc.y, sh.y);
            h3.z = fmaf(h3.z, sc.z, sh.z); h3.w = fmaf(h3.w, sc.w, sh.w);
            h0.x = h0.x > 0.f ? h0.x : 0.f; h0.y = h0.y > 0.f ? h0.y : 0.f;
            h0.z = h0.z > 0.f ? h0.z : 0.f; h0.w = h0.w > 0.f ? h0.w : 0.f;
            h1.x = h1.x > 0.f ? h1.x : 0.f; h1.y = h1.y > 0.f ? h1.y : 0.f;
            h1.z = h1.z > 0.f ? h1.z : 0.f; h1.w = h1.w > 0.f ? h1.w : 0.f;
            h2.x = h2.x > 0.f ? h2.x : 0.f; h2.y = h2.y > 0.f ? h2.y : 0.f;
            h2.z = h2.z > 0.f ? h2.z : 0.f; h2.w = h2.w > 0.f ? h2.w : 0.f;
            h3.x = h3.x > 0.f ? h3.x : 0.f; h3.y = h3.y > 0.f ? h3.y : 0.f;
            h3.z = h3.z > 0.f ? h3.z : 0.f; h3.w = h3.w > 0.f ? h3.w : 0.f;
        }
        acc.x += (h0.x + h1.x) + (h2.x + h3.x);
        acc.y += (h0.y + h1.y) + (h2.y + h3.y);
        acc.z += (h0.z + h1.z) + (h2.z + h3.z);
        acc.w += (h0.w + h1.w) + (h2.w + h3.w);
    }
    for (; e < end; ++e) {
        float4 h0 = ldg4(hsrc + (size_t)esrc[e] * D + d);
        if (AFFINE) {
            h0.x = fmaf(h0.x, sc.x, sh.x); h0.y = fmaf(h0.y, sc.y, sh.y);
            h0.z = fmaf(h0.z, sc.z, sh.z); h0.w = fmaf(h0.w, sc.w, sh.w);
            h0.x = h0.x > 0.f ? h0.x : 0.f; h0.y = h0.y > 0.f ? h0.y : 0.f;
            h0.z = h0.z > 0.f ? h0.z : 0.f; h0.w = h0.w > 0.f ? h0.w : 0.f;
        }
        acc.x += h0.x; acc.y += h0.y; acc.z += h0.z; acc.w += h0.w;
    }

    // split fp32 -> bf16 hi + lo
    unsigned short h0 = f2bf(acc.x), h1 = f2bf(acc.y),
                   h2b = f2bf(acc.z), h3 = f2bf(acc.w);
    ushort4 hv = {h0, h1, h2b, h3};
    ushort4 lv = {f2bf(acc.x - bf2f(h0)), f2bf(acc.y - bf2f(h1)),
                  f2bf(acc.z - bf2f(h2b)), f2bf(acc.w - bf2f(h3))};
    unsigned short* op = aggp + (size_t)node * 256;
    *reinterpret_cast<ushort4*>(op + d) = hv;
    *reinterpret_cast<ushort4*>(op + D + d) = lv;
}

// ---------------------------------------------------------------------------
// Fused MLP on matrix cores, split-bf16 (3-term) for ~fp32 precision.
// Block = 256 thr (4 waves), M-tile = 64 rows (16/wave). Hidden (bf16 hi|lo
// packed u32) in LDS, intra-wave reuse only -> no barrier in GEMM path.
// ---------------------------------------------------------------------------
__global__ __launch_bounds__(256, 2) void k_mlp(
    const unsigned short* __restrict__ aggp,   // [N][256] hi|lo
    float* __restrict__ h2,                    // [N][128] (= d_out)
    const unsigned short* __restrict__ W1p,    // this layer, packed frags
    const unsigned short* __restrict__ W2p,
    const float* __restrict__ b1, const float* __restrict__ b2,
    float* __restrict__ stats, int N)
{
    __shared__ unsigned int hid[64][260];      // +4 pad: 1040B row stride
    __shared__ float s_sum[D], s_sq[D], s_b1[HD], s_b2[D];

    int t = threadIdx.x;
    if (t < D) { s_sum[t] = 0.f; s_sq[t] = 0.f; s_b2[t] = b2[t]; }
    s_b1[t] = b1[t];
    __syncthreads();

    const int w = t >> 6, lane = t & 63;
    const int l15 = lane & 15, l4 = lane >> 4;
    const int row0 = blockIdx.x * 64;
    const int arow = row0 + (w << 4) + l15;    // A-operand row of this lane

    // ---- A fragments for GEMM1 (K=128 -> 4 steps of 32) ----
    bh8 aHi[4], aLo[4];
    if (arow < N) {
        const unsigned short* ap = aggp + (size_t)arow * 256 + l4 * 8;
#pragma unroll
        for (int kk = 0; kk < 4; ++kk) {
            aHi[kk] = *reinterpret_cast<const bh8*>(ap + kk * 32);
            aLo[kk] = *reinterpret_cast<const bh8*>(ap + D + kk * 32);
        }
    } else {
#pragma unroll
        for (int kk = 0; kk < 4; ++kk) {
            aHi[kk] = bh8{0,0,0,0,0,0,0,0};
            aLo[kk] = bh8{0,0,0,0,0,0,0,0};
        }
    }

    // ---- GEMM1: [64x128] x [128x256] ----
    f32x4 acc[16];
#pragma unroll
    for (int nt = 0; nt < 16; ++nt) acc[nt] = f32x4{0.f, 0.f, 0.f, 0.f};
#pragma unroll
    for (int nt = 0; nt < 16; ++nt) {
#pragma unroll
        for (int kk = 0; kk < 4; ++kk) {
            const unsigned short* bp = W1p + ((nt * 4 + kk) * 64 + lane) * 16;
            bh8 bHi = *reinterpret_cast<const bh8*>(bp);
            bh8 bLo = *reinterpret_cast<const bh8*>(bp + 8);
            acc[nt] = __builtin_amdgcn_mfma_f32_16x16x32_bf16(aHi[kk], bHi, acc[nt], 0, 0, 0);
            acc[nt] = __builtin_amdgcn_mfma_f32_16x16x32_bf16(aHi[kk], bLo, acc[nt], 0, 0, 0);
            acc[nt] = __builtin_amdgcn_mfma_f32_16x16x32_bf16(aLo[kk], bHi, acc[nt], 0, 0, 0);
        }
    }

    // ---- epilogue1: bias + relu + split -> hid (D-layout rows) ----
    const int drow_l = (w << 4) + (l4 << 2);   // + r
#pragma unroll
    for (int nt = 0; nt < 16; ++nt) {
        int col = nt * 16 + l15;
        float bias = s_b1[col];
#pragma unroll
        for (int r = 0; r < 4; ++r) {
            float v = acc[nt][r] + bias;
            v = v > 0.f ? v : 0.f;
            unsigned short hi = f2bf(v);
            unsigned short lo = f2bf(v - bf2f(hi));
            hid[drow_l + r][col] = (unsigned int)hi | ((unsigned int)lo << 16);
        }
    }
    // intra-wave LDS reuse only: compiler-inserted lgkmcnt orders write->read

    // ---- GEMM2: [64x256] x [256x128] ----
    f32x4 acc2[8];
#pragma unroll
    for (int nt = 0; nt < 8; ++nt) acc2[nt] = f32x4{0.f, 0.f, 0.f, 0.f};
    const int arow_l = (w << 4) + l15;
#pragma unroll
    for (int kk = 0; kk < 8; ++kk) {
        uint4 w0 = *reinterpret_cast<const uint4*>(&hid[arow_l][kk * 32 + l4 * 8]);
        uint4 w1 = *reinterpret_cast<const uint4*>(&hid[arow_l][kk * 32 + l4 * 8 + 4]);
        bh8 hA, lA;
        hA[0] = (short)(w0.x & 0xffffu); lA[0] = (short)(w0.x >> 16);
        hA[1] = (short)(w0.y & 0xffffu); lA[1] = (short)(w0.y >> 16);
        hA[2] = (short)(w0.z & 0xffffu); lA[2] = (short)(w0.z >> 16);
        hA[3] = (short)(w0.w & 0xffffu); lA[3] = (short)(w0.w >> 16);
        hA[4] = (short)(w1.x & 0xffffu); lA[4] = (short)(w1.x >> 16);
        hA[5] = (short)(w1.y & 0xffffu); lA[5] = (short)(w1.y >> 16);
        hA[6] = (short)(w1.z & 0xffffu); lA[6] = (short)(w1.z >> 16);
        hA[7] = (short)(w1.w & 0xffffu); lA[7] = (short)(w1.w >> 16);
#pragma unroll
        for (int nt = 0; nt < 8; ++nt) {
            const unsigned short* bp = W2p + ((nt * 8 + kk) * 64 + lane) * 16;
            bh8 bHi = *reinterpret_cast<const bh8*>(bp);
            bh8 bLo = *reinterpret_cast<const bh8*>(bp + 8);
            acc2[nt] = __builtin_amdgcn_mfma_f32_16x16x32_bf16(hA, bHi, acc2[nt], 0, 0, 0);
            acc2[nt] = __builtin_amdgcn_mfma_f32_16x16x32_bf16(hA, bLo, acc2[nt], 0, 0, 0);
            acc2[nt] = __builtin_amdgcn_mfma_f32_16x16x32_bf16(lA, bHi, acc2[nt], 0, 0, 0);
        }
    }

    // ---- epilogue2: bias + store h2 + BN partial sums ----
#pragma unroll
    for (int nt = 0; nt < 8; ++nt) {
        int col = nt * 16 + l15;
        float bias = s_b2[col];
        float cs = 0.f, cq = 0.f;
#pragma unroll
        for (int r = 0; r < 4; ++r) {
            int drow = row0 + drow_l + r;
            if (drow < N) {
                float v = acc2[nt][r] + bias;
                h2[(size_t)drow * D + col] = v;
                cs += v; cq += v * v;
            }
        }
        atomicAdd(&s_sum[col], cs);
        atomicAdd(&s_sq[col],  cq);
    }
    __syncthreads();
    if (t < D) {
        atomicAdd(stats + t,     s_sum[t]);
        atomicAdd(stats + D + t, s_sq[t]);
    }
}

// ---------------------------------------------------------------------------
// BN prep: scale/shift from sums
// ---------------------------------------------------------------------------
__global__ __launch_bounds__(128) void k_bnprep(
    const float* __restrict__ stats,
    const float* __restrict__ gamma, const float* __restrict__ beta,
    float* __restrict__ ss, float inv_n)
{
    int d = threadIdx.x;
    float mu  = stats[d] * inv_n;
    float var = stats[D + d] * inv_n - mu * mu;
    float sc  = rsqrtf(var + BN_EPS) * gamma[d];
    ss[d]     = sc;
    ss[D + d] = beta[d] - mu * sc;
}

// ---------------------------------------------------------------------------
// Final BN (no relu), in-place on d_out
// ---------------------------------------------------------------------------
__global__ __launch_bounds__(256) void k_bnfinal(
    float* __restrict__ h, const float* __restrict__ ss, int N)
{
    int idx = blockIdx.x * 256 + threadIdx.x;
    int row = idx >> 5;
    int d   = (idx & 31) * 4;
    if (row >= N) return;
    float4 v  = ldg4(h + (size_t)row * D + d);
    float4 sc = ldg4(ss + d);
    float4 sh = ldg4(ss + D + d);
    float4 o;
    o.x = fmaf(v.x, sc.x, sh.x);
    o.y = fmaf(v.y, sc.y, sh.y);
    o.z = fmaf(v.z, sc.z, sh.z);
    o.w = fmaf(v.w, sc.w, sh.w);
    *reinterpret_cast<float4*>(h + (size_t)row * D + d) = o;
}

// ---------------------------------------------------------------------------
static inline size_t align16(size_t x) { return (x + 15) & ~(size_t)15; }

extern "C" void kernel_launch(void* const* d_in, const int* in_sizes, int n_in,
                              void* d_out, int out_size, void* d_ws, size_t ws_size,
                              hipStream_t stream)
{
    const int*   x     = (const int*)  d_in[0];
    const int*   ei    = (const int*)  d_in[1];
    const int*   ea    = (const int*)  d_in[2];
    const float* ae1   = (const float*)d_in[3];
    const float* ae2   = (const float*)d_in[4];
    const float* be1   = (const float*)d_in[5];   // [5,7,128]
    const float* be2   = (const float*)d_in[6];   // [5,4,128]
    const float* W1    = (const float*)d_in[7];   // [5,128,256]
    const float* b1    = (const float*)d_in[8];   // [5,256]
    const float* W2    = (const float*)d_in[9];   // [5,256,128]
    const float* b2    = (const float*)d_in[10];  // [5,128]
    const float* gamma = (const float*)d_in[11];  // [5,128]
    const float* beta  = (const float*)d_in[12];  // [5,128]

    const int N = in_sizes[0] / 2;
    const int E = in_sizes[1] / 2;

    float* hbuf = (float*)d_out;   // h (layer 0) then h2 of each layer; final BN in place

    // ---- workspace layout (bytes) ----
    char* wsb = (char*)d_ws;
    size_t o = 0;
    int* rowptr = (int*)(wsb + o);          o += align16((size_t)(N + 1) * 4);
    int* counts = (int*)(wsb + o);          o += align16((size_t)N * 9 * 4);
    float* stats = (float*)(wsb + o);       o += align16((size_t)5 * 2 * D * 4);
    const size_t zero_bytes = o;            // rowptr+counts+stats zeroed together
    int* cursor = (int*)(wsb + o);          o += align16((size_t)N * 4);
    int* esrc = (int*)(wsb + o);            o += align16((size_t)E * 4);
    int* bsum = (int*)(wsb + o);            o += align16(1024 * 4);
    int* boff = (int*)(wsb + o);            o += align16(1024 * 4);
    float* ss = (float*)(wsb + o);          o += align16((size_t)5 * 2 * D * 4);
    float* bec = (float*)(wsb + o);         o += align16((size_t)5 * 10 * D * 4);
    unsigned short* W1p = (unsigned short*)(wsb + o); o += align16((size_t)5 * 65536 * 2);
    unsigned short* W2p = (unsigned short*)(wsb + o); o += align16((size_t)5 * 65536 * 2);
    unsigned short* aggp = (unsigned short*)(wsb + o); o += align16((size_t)N * 256 * 2);

    hipMemsetAsync(wsb, 0, zero_bytes, stream);

    const dim3 blk(256);
    const int nb_nodes  = (N * 32 + 255) / 256;
    const int nb_edges  = (E + 255) / 256;
    const int nchunks   = (N + 1023) / 1024;
    const int nb_gather = (N + 7) / 8;
    const int nb_mlp    = (N + 63) / 64;
    const float inv_n   = 1.0f / (float)N;

    k_atom<<<nb_nodes, blk, 0, stream>>>(x, ae1, ae2, hbuf, N);
    k_hist<<<nb_edges, blk, 0, stream>>>(ei, ea, rowptr, counts, E);
    k_scan1<<<nchunks, 1024, 0, stream>>>(rowptr, cursor, bsum, N);
    k_scan2<<<1, 64, 0, stream>>>(bsum, boff, nchunks);
    k_scan3<<<nchunks, 1024, 0, stream>>>(rowptr, cursor, boff, N);
    k_fill<<<nb_edges, blk, 0, stream>>>(ei, cursor, esrc, E);
    k_bec<<<(5 * 10 * D + 255) / 256, blk, 0, stream>>>(be1, be2, bec);
    k_wconv<<<(2 * 5 * 4096 + 255) / 256, blk, 0, stream>>>(W1, W2, W1p, W2p);

    for (int l = 0; l < 5; ++l) {
        float* st = stats + (size_t)l * 2 * D;
        const float* becl = bec + (size_t)l * 10 * D;
        if (l == 0) {
            k_gather<0><<<nb_gather, blk, 0, stream>>>(
                hbuf, rowptr, esrc, counts, becl, nullptr, aggp, N);
        } else {
            k_gather<1><<<nb_gather, blk, 0, stream>>>(
                hbuf, rowptr, esrc, counts, becl, ss + (size_t)(l - 1) * 2 * D, aggp, N);
        }
        k_mlp<<<nb_mlp, blk, 0, stream>>>(
            aggp, hbuf,
            W1p + (size_t)l * 65536, W2p + (size_t)l * 65536,
            b1 + (size_t)l * HD, b2 + (size_t)l * D, st, N);
        k_bnprep<<<1, 128, 0, stream>>>(st, gamma + (size_t)l * D,
                                        beta + (size_t)l * D,
                                        ss + (size_t)l * 2 * D, inv_n);
    }
    k_bnfinal<<<nb_nodes, blk, 0, stream>>>(hbuf, ss + (size_t)4 * 2 * D, N);
}